// Round 9
// baseline (408.567 us; speedup 1.0000x reference)
//
#include <hip/hip_runtime.h>

typedef unsigned int u32;
typedef unsigned char u8;

#define M_DIM 8192   // B*S = 4*2048
#define K_DIM 4096   // I
#define N_DIM 4096   // O
#define GROUPS 64    // I / GROUP_SIZE

typedef int intx4 __attribute__((ext_vector_type(4)));

__device__ __forceinline__ void gload_lds16(const void* g, void* l) {
  __builtin_amdgcn_global_load_lds(
      (const __attribute__((address_space(1))) void*)g,
      (__attribute__((address_space(3))) void*)l, 16, 0, 0);
}

__device__ __forceinline__ u32 pack4(const float* v, float inv) {
  u32 r = 0;
#pragma unroll
  for (int i = 0; i < 4; ++i) {
    int q = (int)__builtin_rintf(v[i] * inv);
    q = q > 127 ? 127 : (q < -127 ? -127 : q);
    r |= ((u32)(u8)(char)q) << (8 * i);
  }
  return r;
}

// ---- fused prep (unchanged from r8, verified) ----
// blocks [0, N_DIM): W path — dequant row o, scatter via perm into LDS,
// block absmax, int8 quantize. blocks [N_DIM, N_DIM+M_DIM/4): X path —
// one x row per WAVE, no LDS/syncthreads, wave shuffle reduce.
__global__ __launch_bounds__(256) void prep_all(
    const float* __restrict__ x, const float* __restrict__ cs,
    const u32* __restrict__ qw, const int* __restrict__ perm,
    const float* __restrict__ scales, const float* __restrict__ zeros,
    u8* __restrict__ xq, u8* __restrict__ wq,
    float* __restrict__ sx, float* __restrict__ sw) {
  __shared__ float rowbuf[K_DIM];   // 16 KB (W path only)
  __shared__ float red[4];
  const int t = threadIdx.x;
  if (blockIdx.x < N_DIM) {
    const int base = t * 16;
    const int o = blockIdx.x;
    const u32* qrow = qw + (size_t)o * (K_DIM / 8);
    const float s = scales[o * GROUPS + (t >> 2)];
    const float z = zeros[o * GROUPS + (t >> 2)];
    uint2 w = *(const uint2*)(qrow + 2 * t);   // elements [16t, 16t+16)
    int4 p0 = *(const int4*)(perm + base + 0);
    int4 p1 = *(const int4*)(perm + base + 4);
    int4 p2 = *(const int4*)(perm + base + 8);
    int4 p3 = *(const int4*)(perm + base + 12);
    float v[16];
    float amax = 0.f;
#pragma unroll
    for (int n = 0; n < 8; ++n) {
      v[n]     = (float)((w.x >> (4 * n)) & 15u) * s + z;
      v[8 + n] = (float)((w.y >> (4 * n)) & 15u) * s + z;
      amax = fmaxf(amax, fmaxf(fabsf(v[n]), fabsf(v[8 + n])));
    }
    rowbuf[p0.x] = v[0];  rowbuf[p0.y] = v[1];
    rowbuf[p0.z] = v[2];  rowbuf[p0.w] = v[3];
    rowbuf[p1.x] = v[4];  rowbuf[p1.y] = v[5];
    rowbuf[p1.z] = v[6];  rowbuf[p1.w] = v[7];
    rowbuf[p2.x] = v[8];  rowbuf[p2.y] = v[9];
    rowbuf[p2.z] = v[10]; rowbuf[p2.w] = v[11];
    rowbuf[p3.x] = v[12]; rowbuf[p3.y] = v[13];
    rowbuf[p3.z] = v[14]; rowbuf[p3.w] = v[15];
#pragma unroll
    for (int off = 32; off; off >>= 1)
      amax = fmaxf(amax, __shfl_xor(amax, off, 64));
    if ((t & 63) == 0) red[t >> 6] = amax;
    __syncthreads();
    amax = fmaxf(fmaxf(red[0], red[1]), fmaxf(red[2], red[3]));
    amax = fmaxf(amax, 1e-20f);
    const float inv = 127.0f / amax;
    uint4 p;
    p.x = pack4(rowbuf + base + 0, inv);
    p.y = pack4(rowbuf + base + 4, inv);
    p.z = pack4(rowbuf + base + 8, inv);
    p.w = pack4(rowbuf + base + 12, inv);
    *(uint4*)(wq + (size_t)o * K_DIM + base) = p;
    if (t == 0) sw[o] = amax * (1.0f / 127.0f);
  } else {
    const int wave = t >> 6, lane = t & 63;
    const size_t m = (size_t)(blockIdx.x - N_DIM) * 4 + wave;
    const float* xr = x + m * K_DIM;
    float v[64];
    float amax = 0.f;
#pragma unroll
    for (int j = 0; j < 4; ++j) {
      const int col = j * 1024 + lane * 16;
#pragma unroll
      for (int u = 0; u < 4; ++u) {
        float4 xv = *(const float4*)(xr + col + u * 4);
        float4 cv = *(const float4*)(cs + col + u * 4);
        float* vp = v + j * 16 + u * 4;
        vp[0] = xv.x * cv.x;
        vp[1] = xv.y * cv.y;
        vp[2] = xv.z * cv.z;
        vp[3] = xv.w * cv.w;
        amax = fmaxf(amax, fmaxf(fmaxf(fabsf(vp[0]), fabsf(vp[1])),
                                 fmaxf(fabsf(vp[2]), fabsf(vp[3]))));
      }
    }
#pragma unroll
    for (int off = 32; off; off >>= 1)
      amax = fmaxf(amax, __shfl_xor(amax, off, 64));
    amax = fmaxf(amax, 1e-20f);
    const float inv = 127.0f / amax;
#pragma unroll
    for (int j = 0; j < 4; ++j) {
      uint4 p;
      p.x = pack4(v + j * 16 + 0, inv);
      p.y = pack4(v + j * 16 + 4, inv);
      p.z = pack4(v + j * 16 + 8, inv);
      p.w = pack4(v + j * 16 + 12, inv);
      *(uint4*)(xq + m * K_DIM + j * 1024 + lane * 16) = p;
    }
    if (lane == 0) sx[m] = amax * (1.0f / 127.0f);
  }
}

// ---- gemm: FAT-WAVE cell. 256x128 tile, 4 waves, per-wave 128x64 out ----
// Campaign status: phase count, prefetch depth, buffer depth, tile size,
// MFMA shape, blocks/CU all NULL (six schedules, MfmaUtil 29.5-34.6%).
// Pipe accounting: MFMA 70us, LDS-read 82us, wall 189us — nothing
// saturated, per-wave serial chains under-overlapped. The never-moved
// knob: per-wave ds_read:MFMA ratio (1:2 in ALL rounds). Here: 8x4
// 16x16 fragments per wave = 12 reads : 32 MFMA (1:2.67); LDS-read
// demand 82->61us (below MFMA floor), barrier/loop overhead per MFMA
// halved. acc[8][4] = 128 VGPR, total ~220 -> 2 blocks/CU (VGPR and
// 72KB tri-buffer LDS agree). Distance-2 prefetch, counted vmcnt(6)
// (6 gload_lds per stage: 4 A + 2 B), one barrier per tile.
// LDS scheme: round-0 verified-zero-conflict 16x16 components: chunk c
// (row r=c>>2, slot p=c&3) holds global chunk p ^ ((r>>1)&3); frag read
// slot qs = q ^ ((lr>>1)&3). __launch_bounds__(256,2) — never raise
// (r4: (512,4) forced 64-VGPR cap -> 13GB scratch).
#define BM 256
#define BN 128
#define BK 64
#define KTILES (K_DIM / BK)   // 64

__global__ __launch_bounds__(256, 2) void gemm_i8(
    const u8* __restrict__ A, const u8* __restrict__ B,
    const float* __restrict__ sx, const float* __restrict__ sw,
    const float* __restrict__ bias, float* __restrict__ out) {
  __shared__ __align__(16) u8 As[3][BM * BK];   // 3 x 16 KB
  __shared__ __align__(16) u8 Bs[3][BN * BK];   // 3 x 8 KB
  const int tid = threadIdx.x;
  const int lane = tid & 63;
  const int wave = tid >> 6;           // 0..3
  const int wm = wave >> 1;            // 0..1 -> 128 M-rows each
  const int wn = wave & 1;             // 0..1 -> 64 N-cols each
  const int q = lane >> 4, lr = lane & 15;
  const int qs = q ^ ((lr >> 1) & 3);  // verified conflict-free read slot

  // XCD-aware bijective swizzle (1024 % 8 == 0)
  const int wg = blockIdx.x;
  const int swzwg = (wg & 7) * 128 + (wg >> 3);
  const int blockN = (swzwg & 31) * BN;   // 32 N-panels
  const int blockM = (swzwg >> 5) * BM;   // 32 M-panels

  const char* Abase = (const char*)(A + (size_t)blockM * K_DIM);
  const char* Bbase = (const char*)(B + (size_t)blockN * K_DIM);

  // staging: A 1024 chunks (4/thread), B 512 chunks (2/thread)
  size_t gOffA[4]; int dOffA[4];
#pragma unroll
  for (int j = 0; j < 4; ++j) {
    const int c = tid + 256 * j;
    const int kc = (c & 3) ^ ((c >> 3) & 3);
    gOffA[j] = (size_t)(c >> 2) * K_DIM + kc * 16;
    dOffA[j] = c * 16;
  }
  size_t gOffB[2]; int dOffB[2];
#pragma unroll
  for (int j = 0; j < 2; ++j) {
    const int c = tid + 256 * j;
    const int kc = (c & 3) ^ ((c >> 3) & 3);
    gOffB[j] = (size_t)(c >> 2) * K_DIM + kc * 16;
    dOffB[j] = c * 16;
  }

  const int aoff = (wm * 128 + lr) * 64 + qs * 16;   // + mi*1024, mi 0..7
  const int boff = (wn * 64 + lr) * 64 + qs * 16;    // + ni*1024, ni 0..3

  intx4 acc[8][4];
#pragma unroll
  for (int i = 0; i < 8; ++i)
#pragma unroll
    for (int j = 0; j < 4; ++j) acc[i][j] = (intx4)0;

  auto stage = [&](int t, int b) {
    const size_t koff = (size_t)t * BK;
#pragma unroll
    for (int j = 0; j < 4; ++j)
      gload_lds16(Abase + gOffA[j] + koff, &As[b][dOffA[j]]);
#pragma unroll
    for (int j = 0; j < 2; ++j)
      gload_lds16(Bbase + gOffB[j] + koff, &Bs[b][dOffB[j]]);
  };

  // prologue: tiles 0,1 in flight (12 loads); certify tile 0 (6 left flying)
  stage(0, 0);
  stage(1, 1);
  asm volatile("s_waitcnt vmcnt(6)" ::: "memory");
  asm volatile("s_barrier" ::: "memory");

  int bc = 0, bs = 2;   // compute buf for t; stage buf for t+2
  for (int t = 0; t < KTILES; ++t) {
    if (t + 2 < KTILES) stage(t + 2, bs);

    const u8* Ab = &As[bc][0];
    const u8* Bb = &Bs[bc][0];
    intx4 bf[4], af[8];
#pragma unroll
    for (int ni = 0; ni < 4; ++ni)
      bf[ni] = *(const intx4*)(Bb + boff + ni * 1024);
#pragma unroll
    for (int mi = 0; mi < 8; ++mi)
      af[mi] = *(const intx4*)(Ab + aoff + mi * 1024);

    __builtin_amdgcn_s_setprio(1);
#pragma unroll
    for (int mi = 0; mi < 8; ++mi)
#pragma unroll
      for (int ni = 0; ni < 4; ++ni)
        acc[mi][ni] = __builtin_amdgcn_mfma_i32_16x16x64_i8(
            af[mi], bf[ni], acc[mi][ni], 0, 0, 0);
    __builtin_amdgcn_s_setprio(0);

    // certify t+1; t+2's 6 loads stay in flight
    if (t + 2 < KTILES) {
      asm volatile("s_waitcnt vmcnt(6)" ::: "memory");
    } else if (t + 1 < KTILES) {
      asm volatile("s_waitcnt vmcnt(0)" ::: "memory");   // pipeline drain
    }
    if (t + 1 < KTILES) asm volatile("s_barrier" ::: "memory");

    bc = (bc == 2) ? 0 : bc + 1;
    bs = (bs == 2) ? 0 : bs + 1;
  }

  // epilogue (verified 16x16 C/D map): col slot = lane&15, row = quad*4+reg
#pragma unroll
  for (int ni = 0; ni < 4; ++ni) {
    const int col = blockN + wn * 64 + ni * 16 + lr;
    const float swv = sw[col];
    const float bv = bias[col];
#pragma unroll
    for (int mi = 0; mi < 8; ++mi) {
      const int row0 = blockM + wm * 128 + mi * 16 + q * 4;
#pragma unroll
      for (int r = 0; r < 4; ++r) {
        const float s = sx[row0 + r] * swv;
        out[(size_t)(row0 + r) * N_DIM + col] = (float)acc[mi][ni][r] * s + bv;
      }
    }
  }
}

extern "C" void kernel_launch(void* const* d_in, const int* in_sizes, int n_in,
                              void* d_out, int out_size, void* d_ws, size_t ws_size,
                              hipStream_t stream) {
  const float* x      = (const float*)d_in[0];
  const float* cs     = (const float*)d_in[1];
  const u32*   qw     = (const u32*)d_in[2];
  const int*   perm   = (const int*)d_in[3];
  const float* scales = (const float*)d_in[4];
  const float* zeros  = (const float*)d_in[5];
  const float* bias   = (const float*)d_in[6];
  float* out = (float*)d_out;

  u8* xq = (u8*)d_ws;                               // 32 MiB: M*K i8 (natural)
  u8* wq = xq + (size_t)M_DIM * K_DIM;              // 16 MiB: N*K i8 (perm-scattered)
  float* sx = (float*)(wq + (size_t)N_DIM * K_DIM); // 32 KiB
  float* sw = sx + M_DIM;                           // 16 KiB

  hipLaunchKernelGGL(prep_all, dim3(N_DIM + M_DIM / 4), dim3(256), 0, stream,
                     x, cs, qw, perm, scales, zeros, xq, wq, sx, sw);
  hipLaunchKernelGGL(gemm_i8, dim3((M_DIM / BM) * (N_DIM / BN)), dim3(256), 0,
                     stream, xq, wq, sx, sw, bias, out);
}